// Round 18
// baseline (596.704 us; speedup 1.0000x reference)
//
#include <hip/hip_runtime.h>
#include <cstdint>
#include <cstddef>

#define E_TOT 131072
#define NNODES 8192

typedef __attribute__((ext_vector_type(8))) short bf16x8;
typedef __attribute__((ext_vector_type(4))) float f32x4;
typedef unsigned short u16;
typedef unsigned int u32;

__device__ __forceinline__ u16 f2bf(float f) {
    u32 u = __builtin_bit_cast(u32, f);
    u32 r = (u + 0x7FFFu + ((u >> 16) & 1u)) >> 16;
    return (u16)r;
}

__device__ __forceinline__ void gload16(const u16* g, u16* l) {
    __builtin_amdgcn_global_load_lds((const __attribute__((address_space(1))) void*)g,
                                     (__attribute__((address_space(3))) void*)l, 16, 0, 0);
}

// swizzled LDS fragment read: rows 128 B; byte col XORed with (row&7)<<4
__device__ __forceinline__ bf16x8 lds_frag(const u16* base, int row, int bytecol) {
    return *(const bf16x8*)((const char*)base + row * 128 + (bytecol ^ ((row & 7) << 4)));
}

// ---- weight convert + transpose: dst[n*K+k] = bf16(src[k*N+n]) ----
__global__ void wconv_kernel(const float* __restrict__ src, u16* __restrict__ dst,
                             int K, int N) {
    int idx = blockIdx.x * 256 + threadIdx.x;
    if (idx >= N * K) return;
    int n = idx / K, k = idx - n * K;
    dst[idx] = f2bf(src[(size_t)k * N + n]);
}

// ---- envelope(r) and Y = [1, sqrt3*nhat] per edge ----
__global__ void envy_kernel(const float* __restrict__ vectors, float* __restrict__ env,
                            float4* __restrict__ Y) {
    int e = blockIdx.x * 256 + threadIdx.x;
    float vx = vectors[3 * e + 0], vy = vectors[3 * e + 1], vz = vectors[3 * e + 2];
    float r2 = vx * vx + vy * vy + vz * vz;
    float r = sqrtf(r2);
    float u6 = r2 * r2 * r2;
    float f = 1.0f + u6 * (-28.0f + 48.0f * r - 21.0f * r2);
    env[e] = (r < 1.0f) ? f : 0.0f;
    float inv = 1.7320508075688772f / r;
    Y[e] = make_float4(1.0f, vx * inv, vy * inv, vz * inv);
}

// ---- counting sort: histogram ----
__global__ void hist_kernel(const int* __restrict__ senders, int* __restrict__ cnt) {
    int e = blockIdx.x * 256 + threadIdx.x;
    atomicAdd(&cnt[senders[e]], 1);
}

// ---- single-block exclusive scan of 8192 counts -> off[8193], curs[8192] ----
__launch_bounds__(1024)
__global__ void scan_kernel(const int* __restrict__ cnt, int* __restrict__ off,
                            int* __restrict__ curs) {
    __shared__ int part[1024];
    const int t = threadIdx.x;
    int local[8];
    int s = 0;
#pragma unroll
    for (int j = 0; j < 8; ++j) { local[j] = cnt[t * 8 + j]; s += local[j]; }
    part[t] = s;
    __syncthreads();
    for (int d = 1; d < 1024; d <<= 1) {
        int v = (t >= d) ? part[t - d] : 0;
        __syncthreads();
        part[t] += v;
        __syncthreads();
    }
    int run = part[t] - s; // exclusive base
#pragma unroll
    for (int j = 0; j < 8; ++j) {
        off[t * 8 + j] = run;
        curs[t * 8 + j] = run;
        run += local[j];
    }
    if (t == 1023) off[8192] = run;
}

// ---- perm build: perm[pos] = e ----
__global__ void permbuild_kernel(const int* __restrict__ senders, int* __restrict__ curs,
                                 int* __restrict__ perm) {
    int e = blockIdx.x * 256 + threadIdx.x;
    int s = senders[e];
    int p = atomicAdd(&curs[s], 1);
    perm[p] = e;
}

// ---- gather segment-sum: agg[n][m][:] = sum_{e in seg(n)} w[e][m]*Y[e] ----
__launch_bounds__(256)
__global__ void gather_kernel(const float* __restrict__ w, const float4* __restrict__ Y,
                              const int* __restrict__ off, const int* __restrict__ perm,
                              float4* __restrict__ agg) {
    const int t = threadIdx.x;
    const int n = blockIdx.x * 4 + (t >> 6);
    const int m = t & 63;
    const int beg = off[n], end = off[n + 1];
    float4 acc = make_float4(0.f, 0.f, 0.f, 0.f);
    for (int i = beg; i < end; ++i) {
        int e = perm[i];
        float wv = w[(size_t)e * 64 + m];
        float4 y = Y[e];
        acc.x += wv * y.x; acc.y += wv * y.y; acc.z += wv * y.z; acc.w += wv * y.w;
    }
    agg[(size_t)n * 64 + m] = acc;
}

// ---- fused: w = x @ W_w / sqrt(512) AND XB = bf16(x), XB K-TILED [8][E][64] ----
__launch_bounds__(256)
__global__ void wgemm_kernel(const float* __restrict__ x, const u16* __restrict__ Wt,
                             u16* __restrict__ XB, float* __restrict__ w) {
    __shared__ u16 As[128 * 72];
    __shared__ u16 Bs[64 * 72];
    const int e0 = blockIdx.x * 128;
    const int t = threadIdx.x, lane = t & 63, wid = t >> 6;
    const int lr = lane & 15, lh = lane >> 4;
    const int r8 = t >> 3, c8 = t & 7;
    f32x4 acc[2][4] = {};
    for (int kt = 0; kt < 8; ++kt) {
        const int kk = kt << 6;
#pragma unroll
        for (int i = 0; i < 4; ++i) {
            int row = i * 32 + r8;
            const float* gx = x + (size_t)(e0 + row) * 512 + kk + c8 * 8;
            float4 a = *(const float4*)gx;
            float4 b = *(const float4*)(gx + 4);
            union { u16 h[8]; uint4 v; } p;
            p.h[0] = f2bf(a.x); p.h[1] = f2bf(a.y); p.h[2] = f2bf(a.z); p.h[3] = f2bf(a.w);
            p.h[4] = f2bf(b.x); p.h[5] = f2bf(b.y); p.h[6] = f2bf(b.z); p.h[7] = f2bf(b.w);
            *(uint4*)((char*)As + row * 144 + c8 * 16) = p.v;
            *(uint4*)(XB + ((size_t)kt * E_TOT + e0 + row) * 64 + c8 * 8) = p.v;
        }
#pragma unroll
        for (int i = 0; i < 2; ++i) {
            int row = i * 32 + r8;
            const u16* g = Wt + (size_t)row * 512 + kk + c8 * 8;
            *(uint4*)((char*)Bs + row * 144 + c8 * 16) = *(const uint4*)g;
        }
        __syncthreads();
#pragma unroll
        for (int k2 = 0; k2 < 2; ++k2) {
            bf16x8 af[2], bfr[4];
#pragma unroll
            for (int m = 0; m < 2; ++m)
                af[m] = *(const bf16x8*)((const char*)As + (wid * 32 + m * 16 + lr) * 144 + k2 * 64 + lh * 16);
#pragma unroll
            for (int n = 0; n < 4; ++n)
                bfr[n] = *(const bf16x8*)((const char*)Bs + (n * 16 + lr) * 144 + k2 * 64 + lh * 16);
#pragma unroll
            for (int m = 0; m < 2; ++m)
#pragma unroll
                for (int n = 0; n < 4; ++n)
                    acc[m][n] = __builtin_amdgcn_mfma_f32_16x16x32_bf16(af[m], bfr[n], acc[m][n], 0, 0, 0);
        }
        __syncthreads();
    }
    const float s = 0.044194173824159216f; // 1/sqrt(512)
#pragma unroll
    for (int m = 0; m < 2; ++m)
#pragma unroll
        for (int n = 0; n < 4; ++n)
#pragma unroll
            for (int j = 0; j < 4; ++j) {
                int e = e0 + wid * 32 + m * 16 + lh * 4 + j;
                w[(size_t)e * 64 + n * 16 + lr] = acc[m][n][j] * s;
            }
}

// ---- edge products: scal (bf16, K-TILED [2][E][64]) + V_out GEMM ----
__launch_bounds__(256)
__global__ void edge_kernel(const int* __restrict__ senders, const float4* __restrict__ agg4,
                            const float4* __restrict__ V4, const u16* __restrict__ Wlt,
                            u16* __restrict__ scal, float* __restrict__ Vout) {
    __shared__ u16 a_lds[3][32][200];
    __shared__ u16 w_lds[64 * 200];
    const int t = threadIdx.x;
    const int e0 = blockIdx.x * 32;
#pragma unroll
    for (int i = 0; i < 6; ++i) {
        int c = i * 256 + t;
        int row = c / 24, off = (c % 24) * 8;
        *(uint4*)((char*)w_lds + row * 400 + off * 2) = ((const uint4*)Wlt)[c];
    }
    const float invs3 = 0.5773502691896258f;
    const float invs2 = 0.7071067811865476f;
    const float EPS = 0.24253562503633297f;
#pragma unroll
    for (int i = 0; i < 8; ++i) {
        int el = i * 4 + (t >> 6);
        int m = t & 63;
        int e = e0 + el;
        int s = senders[e];
        float4 a = agg4[(size_t)s * 64 + m];
        a.x *= EPS; a.y *= EPS; a.z *= EPS; a.w *= EPS;
        float4 b = V4[(size_t)e * 64 + m];
        float s0 = a.x * b.x;
        float s1 = (a.y * b.y + a.z * b.z + a.w * b.w) * invs3;
        scal[(size_t)e * 64 + m] = f2bf(s0);                       // K-tile 0
        scal[(size_t)E_TOT * 64 + (size_t)e * 64 + m] = f2bf(s1);  // K-tile 1
        float cx = (a.z * b.w - a.w * b.z) * invs2;
        float cy = (a.w * b.y - a.y * b.w) * invs2;
        float cz = (a.y * b.z - a.z * b.y) * invs2;
        a_lds[0][el][m] = f2bf(a.x * b.y);
        a_lds[0][el][64 + m] = f2bf(a.y * b.x);
        a_lds[0][el][128 + m] = f2bf(cx);
        a_lds[1][el][m] = f2bf(a.x * b.z);
        a_lds[1][el][64 + m] = f2bf(a.z * b.x);
        a_lds[1][el][128 + m] = f2bf(cy);
        a_lds[2][el][m] = f2bf(a.x * b.w);
        a_lds[2][el][64 + m] = f2bf(a.w * b.x);
        a_lds[2][el][128 + m] = f2bf(cz);
    }
    __syncthreads();
    const int lane = t & 63, wid = t >> 6;
    const int lr = lane & 15, lh = lane >> 4;
    f32x4 acc[3][2] = {};
    for (int kt = 0; kt < 6; ++kt) {
        bf16x8 bfr = *(const bf16x8*)((const char*)w_lds + (wid * 16 + lr) * 400 + kt * 64 + lh * 16);
#pragma unroll
        for (int c = 0; c < 3; ++c)
#pragma unroll
            for (int m = 0; m < 2; ++m) {
                bf16x8 afr = *(const bf16x8*)((const char*)a_lds + ((c * 32 + m * 16 + lr) * 400) + kt * 64 + lh * 16);
                acc[c][m] = __builtin_amdgcn_mfma_f32_16x16x32_bf16(afr, bfr, acc[c][m], 0, 0, 0);
            }
    }
    __syncthreads();
    float* ot = (float*)a_lds;
    const float sc = 0.07216878364870323f; // 1/sqrt(192)
#pragma unroll
    for (int c = 0; c < 3; ++c)
#pragma unroll
        for (int m = 0; m < 2; ++m)
#pragma unroll
            for (int j = 0; j < 4; ++j) {
                int row = m * 16 + lh * 4 + j;
                int mul = wid * 16 + lr;
                ot[row * 192 + mul * 3 + c] = acc[c][m][j] * sc;
            }
    __syncthreads();
    float4* vo = (float4*)(Vout + (size_t)e0 * 192);
#pragma unroll
    for (int i = 0; i < 6; ++i)
        vo[i * 256 + t] = ((float4*)ot)[i * 256 + t];
}

// ---- MLP GEMM v11: BM=128 x BN=512 (FULL N), BK=64. A staged ONCE
//      (no 2x A-pass), B (L2-resident weights) 64 KB/step. 8 waves (2Mx4N),
//      wave-tile 64x128 -> 64 MFMA : 24 ds_read per step (vs 16:8 before).
//      Persistent: 256 blocks x 4 mt-tiles, r14's exact proven barrier
//      pattern: top {vmcnt(10);s_barrier} (all but newest 10 retired =>
//      current tile landed, stores irrelevant), MFMA, {lgkm(0);s_barrier},
//      issue(g+2). LDS dbuf 2 x (16K A + 64K B) = 160 KB (144 KB proven r12).
//      A K-tiled [K/64][E][64] => per-step A-fetch = contiguous 16 KB.
//      MODE 0: silu->bf16 K-tiled out; MODE 1: env-scale->f32 row-major.
template <int MODE, int K>
__launch_bounds__(512)
__global__ void mlp_gemm(const u16* __restrict__ A, const u16* __restrict__ A2,
                         const u16* __restrict__ Bt, const float scale,
                         const float* __restrict__ env,
                         u16* __restrict__ outb, float* __restrict__ outf) {
    constexpr int NKT = K >> 6;
    constexpr int NSTEP = NKT * 4;     // 4 mt-tiles per block
    __shared__ u16 lds[81920];         // 160 KiB: buf b at b*40960; A +0, B +8192
    const int b = blockIdx.x;          // 0..255
    const int t = threadIdx.x, lane = t & 63, wid = t >> 6;
    const int wm = wid >> 2, wn = wid & 3;  // 2 x 4 wave grid; wave-tile 64 x 128
    const int lr = lane & 15, lh = lane >> 4;
    f32x4 acc[4][8] = {};

    auto issue = [&](int g) {
        const int tile = g / NKT;
        const int kt = g - tile * NKT;
        const int mt = b * 4 + tile;
        const int e0 = mt << 7;
        const int kk = kt << 6;
        u16* buf = lds + (g & 1) * 40960;
        // A: 128 rows x 64 K = 1024 chunks (2/thread), K-tiled source
        const u16* abase;
        int kt64;
        if (A2 && kk >= 512) { abase = A2; kt64 = (kk - 512) >> 6; }
        else                 { abase = A;  kt64 = kk >> 6; }
#pragma unroll
        for (int i = 0; i < 2; ++i) {
            const int c = i * 512 + t;
            const int rowin = c >> 3;
            const int scol = ((c & 7) ^ (rowin & 7)) << 3;
            gload16(abase + ((size_t)kt64 * E_TOT + e0 + rowin) * 64 + scol,
                    buf + (size_t)c * 8);
        }
        // B: 512 rows x 64 K = 4096 chunks (8/thread)
#pragma unroll
        for (int i = 0; i < 8; ++i) {
            const int c = i * 512 + t;
            const int rowin = c >> 3;
            const int scol = ((c & 7) ^ (rowin & 7)) << 3;
            gload16(Bt + (size_t)rowin * K + kk + scol,
                    buf + 8192 + (size_t)c * 8);
        }
    };

    issue(0);
    issue(1);
    for (int g = 0; g < NSTEP; ++g) {
        const int tile = g / NKT;
        const int kt = g - tile * NKT;
        // fused wait+barrier: all but newest 10 retired => tile g landed
        if (g + 1 >= NSTEP) asm volatile("s_waitcnt vmcnt(0)\ns_barrier" ::: "memory");
        else                asm volatile("s_waitcnt vmcnt(10)\ns_barrier" ::: "memory");
        const u16* Ab = lds + (g & 1) * 40960;
        const u16* Bb = Ab + 8192;
        __builtin_amdgcn_s_setprio(1);
#pragma unroll
        for (int k2 = 0; k2 < 2; ++k2) {
            bf16x8 af[4], bfr[8];
#pragma unroll
            for (int m = 0; m < 4; ++m)
                af[m] = lds_frag(Ab, wm * 64 + m * 16 + lr, k2 * 64 + lh * 16);
#pragma unroll
            for (int n = 0; n < 8; ++n)
                bfr[n] = lds_frag(Bb, wn * 128 + n * 16 + lr, k2 * 64 + lh * 16);
#pragma unroll
            for (int m = 0; m < 4; ++m)
#pragma unroll
                for (int n = 0; n < 8; ++n)
                    acc[m][n] = __builtin_amdgcn_mfma_f32_16x16x32_bf16(af[m], bfr[n], acc[m][n], 0, 0, 0);
        }
        __builtin_amdgcn_s_setprio(0);
        // all waves' reads of buf g&1 done -> safe for issue(g+2) to refill it
        asm volatile("s_waitcnt lgkmcnt(0)\ns_barrier" ::: "memory");
        if (g + 2 < NSTEP) issue(g + 2);
        if (kt == NKT - 1) {
            // epilogue for mt-tile (overlaps next tile's in-flight loads)
            const int mt = b * 4 + tile;
            const int e0 = mt << 7;
#pragma unroll
            for (int m = 0; m < 4; ++m) {
#pragma unroll
                for (int j = 0; j < 4; ++j) {
                    const int row = e0 + wm * 64 + m * 16 + lh * 4 + j;
                    float ev = (MODE == 1) ? env[row] : 0.0f;
#pragma unroll
                    for (int n = 0; n < 8; ++n) {
                        const int col = wn * 128 + n * 16 + lr;
                        float v = acc[m][n][j] * scale;
                        if (MODE == 0) {
                            float sv = v / (1.0f + __expf(-v));
                            outb[((size_t)(col >> 6) * E_TOT + row) * 64 + (col & 63)] = f2bf(sv);
                        } else {
                            outf[(size_t)row * 512 + col] = v * ev;
                        }
                    }
                }
            }
#pragma unroll
            for (int m = 0; m < 4; ++m)
#pragma unroll
                for (int n = 0; n < 8; ++n)
                    acc[m][n] = f32x4{0.f, 0.f, 0.f, 0.f};
        }
    }
}

extern "C" void kernel_launch(void* const* d_in, const int* in_sizes, int n_in,
                              void* d_out, int out_size, void* d_ws, size_t ws_size,
                              hipStream_t stream) {
    const float* vectors = (const float*)d_in[0];
    const float* x       = (const float*)d_in[1];
    const float* V       = (const float*)d_in[2];
    const int*   senders = (const int*)d_in[3];
    const float* W_w     = (const float*)d_in[4];
    const float* W1      = (const float*)d_in[5];
    const float* W2      = (const float*)d_in[6];
    const float* W3      = (const float*)d_in[7];
    const float* W_lin   = (const float*)d_in[8];
    float* out = (float*)d_out;
    char* ws = (char*)d_ws;

    u16*    XB   = (u16*)(ws + 0x0);          // E*512 bf16 (K-tiled [8][E][64])
    u16*    H1   = (u16*)(ws + 0x8000000);    // E*512 bf16 (K-tiled)
    u16*    SCAL = (u16*)(ws + 0x10000000);   // E*128 bf16 (K-tiled [2][E][64])
    float*  AGG  = (float*)(ws + 0x12000000); // 8192*256 f32
    float*  ENV  = (float*)(ws + 0x12800000); // E f32
    float4* Yb   = (float4*)(ws + 0x12880000);// E float4
    float*  Wbuf = (float*)(ws + 0x12A80000); // E*64 f32
    u16*    WT   = (u16*)(ws + 0x14A80000);   // weights bf16
    u16* Wwt = WT;                 // 64 x 512
    u16* W1t = Wwt + 64 * 512;     // 512 x 640
    u16* W2t = W1t + 512 * 640;    // 512 x 512
    u16* W3t = W2t + 512 * 512;    // 512 x 512
    u16* Wlt = W3t + 512 * 512;    // 64 x 192
    u16* H2 = XB;                  // reuse XB for h2 (K-tiled; GEMM1 done reading)
    // sort scratch
    int* COUNT = (int*)(ws + 0x15000000);     // 8192
    int* OFF   = (int*)(ws + 0x15010000);     // 8193
    int* CURS  = (int*)(ws + 0x15020000);     // 8192
    int* PERM  = (int*)(ws + 0x15030000);     // E

    hipMemsetAsync(COUNT, 0, NNODES * sizeof(int), stream);

    wconv_kernel<<<(64 * 512) / 256, 256, 0, stream>>>(W_w, Wwt, 512, 64);
    wconv_kernel<<<(512 * 640) / 256, 256, 0, stream>>>(W1, W1t, 640, 512);
    wconv_kernel<<<(512 * 512) / 256, 256, 0, stream>>>(W2, W2t, 512, 512);
    wconv_kernel<<<(512 * 512) / 256, 256, 0, stream>>>(W3, W3t, 512, 512);
    wconv_kernel<<<(64 * 192) / 256, 256, 0, stream>>>(W_lin, Wlt, 192, 64);

    envy_kernel<<<E_TOT / 256, 256, 0, stream>>>(vectors, ENV, Yb);

    hist_kernel<<<E_TOT / 256, 256, 0, stream>>>(senders, COUNT);
    scan_kernel<<<1, 1024, 0, stream>>>(COUNT, OFF, CURS);
    permbuild_kernel<<<E_TOT / 256, 256, 0, stream>>>(senders, CURS, PERM);

    // fused x->bf16 conversion (K-tiled XB) + w-GEMM
    wgemm_kernel<<<E_TOT / 128, 256, 0, stream>>>(x, Wwt, XB, Wbuf);
    gather_kernel<<<NNODES / 4, 256, 0, stream>>>(Wbuf, Yb, OFF, PERM, (float4*)AGG);

    edge_kernel<<<E_TOT / 32, 256, 0, stream>>>(senders, (const float4*)AGG, (const float4*)V,
                                                Wlt, SCAL, out + (size_t)E_TOT * 512);

    const float s640 = 0.03952847075210474f;  // 1/sqrt(640)
    const float s512 = 0.044194173824159216f; // 1/sqrt(512)
    // persistent grid: 256 blocks x 4 mt-tiles (BN = full 512)
    mlp_gemm<0, 640><<<256, 512, 0, stream>>>(XB, SCAL, W1t, s640, nullptr, H1, nullptr);
    mlp_gemm<0, 512><<<256, 512, 0, stream>>>(H1, nullptr, W2t, s512, nullptr, H2, nullptr);
    mlp_gemm<1, 512><<<256, 512, 0, stream>>>(H2, nullptr, W3t, s512, ENV, nullptr, out);
}

// Round 20
// 572.656 us; speedup vs baseline: 1.0420x; 1.0420x over previous
//
#include <hip/hip_runtime.h>
#include <cstdint>
#include <cstddef>

#define E_TOT 131072
#define NNODES 8192

typedef __attribute__((ext_vector_type(8))) short bf16x8;
typedef __attribute__((ext_vector_type(4))) float f32x4;
typedef unsigned short u16;
typedef unsigned int u32;

__device__ __forceinline__ u16 f2bf(float f) {
    u32 u = __builtin_bit_cast(u32, f);
    u32 r = (u + 0x7FFFu + ((u >> 16) & 1u)) >> 16;
    return (u16)r;
}

__device__ __forceinline__ void gload16(const u16* g, u16* l) {
    __builtin_amdgcn_global_load_lds((const __attribute__((address_space(1))) void*)g,
                                     (__attribute__((address_space(3))) void*)l, 16, 0, 0);
}

// swizzled LDS fragment read: rows 128 B; byte col XORed with (row&7)<<4
__device__ __forceinline__ bf16x8 lds_frag(const u16* base, int row, int bytecol) {
    return *(const bf16x8*)((const char*)base + row * 128 + (bytecol ^ ((row & 7) << 4)));
}

// ---- weight convert + transpose: dst[n*K+k] = bf16(src[k*N+n]) ----
__global__ void wconv_kernel(const float* __restrict__ src, u16* __restrict__ dst,
                             int K, int N) {
    int idx = blockIdx.x * 256 + threadIdx.x;
    if (idx >= N * K) return;
    int n = idx / K, k = idx - n * K;
    dst[idx] = f2bf(src[(size_t)k * N + n]);
}

// ---- envelope(r) and Y = [1, sqrt3*nhat] per edge ----
__global__ void envy_kernel(const float* __restrict__ vectors, float* __restrict__ env,
                            float4* __restrict__ Y) {
    int e = blockIdx.x * 256 + threadIdx.x;
    float vx = vectors[3 * e + 0], vy = vectors[3 * e + 1], vz = vectors[3 * e + 2];
    float r2 = vx * vx + vy * vy + vz * vz;
    float r = sqrtf(r2);
    float u6 = r2 * r2 * r2;
    float f = 1.0f + u6 * (-28.0f + 48.0f * r - 21.0f * r2);
    env[e] = (r < 1.0f) ? f : 0.0f;
    float inv = 1.7320508075688772f / r;
    Y[e] = make_float4(1.0f, vx * inv, vy * inv, vz * inv);
}

// ---- counting sort: histogram ----
__global__ void hist_kernel(const int* __restrict__ senders, int* __restrict__ cnt) {
    int e = blockIdx.x * 256 + threadIdx.x;
    atomicAdd(&cnt[senders[e]], 1);
}

// ---- single-block exclusive scan of 8192 counts -> off[8193], curs[8192] ----
__launch_bounds__(1024)
__global__ void scan_kernel(const int* __restrict__ cnt, int* __restrict__ off,
                            int* __restrict__ curs) {
    __shared__ int part[1024];
    const int t = threadIdx.x;
    int local[8];
    int s = 0;
#pragma unroll
    for (int j = 0; j < 8; ++j) { local[j] = cnt[t * 8 + j]; s += local[j]; }
    part[t] = s;
    __syncthreads();
    for (int d = 1; d < 1024; d <<= 1) {
        int v = (t >= d) ? part[t - d] : 0;
        __syncthreads();
        part[t] += v;
        __syncthreads();
    }
    int run = part[t] - s; // exclusive base
#pragma unroll
    for (int j = 0; j < 8; ++j) {
        off[t * 8 + j] = run;
        curs[t * 8 + j] = run;
        run += local[j];
    }
    if (t == 1023) off[8192] = run;
}

// ---- perm build: perm[pos] = e ----
__global__ void permbuild_kernel(const int* __restrict__ senders, int* __restrict__ curs,
                                 int* __restrict__ perm) {
    int e = blockIdx.x * 256 + threadIdx.x;
    int s = senders[e];
    int p = atomicAdd(&curs[s], 1);
    perm[p] = e;
}

// ---- gather segment-sum: agg[n][m][:] = sum_{e in seg(n)} w[e][m]*Y[e] ----
__launch_bounds__(256)
__global__ void gather_kernel(const float* __restrict__ w, const float4* __restrict__ Y,
                              const int* __restrict__ off, const int* __restrict__ perm,
                              float4* __restrict__ agg) {
    const int t = threadIdx.x;
    const int n = blockIdx.x * 4 + (t >> 6);
    const int m = t & 63;
    const int beg = off[n], end = off[n + 1];
    float4 acc = make_float4(0.f, 0.f, 0.f, 0.f);
    for (int i = beg; i < end; ++i) {
        int e = perm[i];
        float wv = w[(size_t)e * 64 + m];
        float4 y = Y[e];
        acc.x += wv * y.x; acc.y += wv * y.y; acc.z += wv * y.z; acc.w += wv * y.w;
    }
    agg[(size_t)n * 64 + m] = acc;
}

// ---- fused: w = x @ W_w / sqrt(512) AND XB = bf16(x), XB K-TILED [8][E][64] ----
__launch_bounds__(256)
__global__ void wgemm_kernel(const float* __restrict__ x, const u16* __restrict__ Wt,
                             u16* __restrict__ XB, float* __restrict__ w) {
    __shared__ u16 As[128 * 72];
    __shared__ u16 Bs[64 * 72];
    const int e0 = blockIdx.x * 128;
    const int t = threadIdx.x, lane = t & 63, wid = t >> 6;
    const int lr = lane & 15, lh = lane >> 4;
    const int r8 = t >> 3, c8 = t & 7;
    f32x4 acc[2][4] = {};
    for (int kt = 0; kt < 8; ++kt) {
        const int kk = kt << 6;
#pragma unroll
        for (int i = 0; i < 4; ++i) {
            int row = i * 32 + r8;
            const float* gx = x + (size_t)(e0 + row) * 512 + kk + c8 * 8;
            float4 a = *(const float4*)gx;
            float4 b = *(const float4*)(gx + 4);
            union { u16 h[8]; uint4 v; } p;
            p.h[0] = f2bf(a.x); p.h[1] = f2bf(a.y); p.h[2] = f2bf(a.z); p.h[3] = f2bf(a.w);
            p.h[4] = f2bf(b.x); p.h[5] = f2bf(b.y); p.h[6] = f2bf(b.z); p.h[7] = f2bf(b.w);
            *(uint4*)((char*)As + row * 144 + c8 * 16) = p.v;
            *(uint4*)(XB + ((size_t)kt * E_TOT + e0 + row) * 64 + c8 * 8) = p.v;
        }
#pragma unroll
        for (int i = 0; i < 2; ++i) {
            int row = i * 32 + r8;
            const u16* g = Wt + (size_t)row * 512 + kk + c8 * 8;
            *(uint4*)((char*)Bs + row * 144 + c8 * 16) = *(const uint4*)g;
        }
        __syncthreads();
#pragma unroll
        for (int k2 = 0; k2 < 2; ++k2) {
            bf16x8 af[2], bfr[4];
#pragma unroll
            for (int m = 0; m < 2; ++m)
                af[m] = *(const bf16x8*)((const char*)As + (wid * 32 + m * 16 + lr) * 144 + k2 * 64 + lh * 16);
#pragma unroll
            for (int n = 0; n < 4; ++n)
                bfr[n] = *(const bf16x8*)((const char*)Bs + (n * 16 + lr) * 144 + k2 * 64 + lh * 16);
#pragma unroll
            for (int m = 0; m < 2; ++m)
#pragma unroll
                for (int n = 0; n < 4; ++n)
                    acc[m][n] = __builtin_amdgcn_mfma_f32_16x16x32_bf16(af[m], bfr[n], acc[m][n], 0, 0, 0);
        }
        __syncthreads();
    }
    const float s = 0.044194173824159216f; // 1/sqrt(512)
#pragma unroll
    for (int m = 0; m < 2; ++m)
#pragma unroll
        for (int n = 0; n < 4; ++n)
#pragma unroll
            for (int j = 0; j < 4; ++j) {
                int e = e0 + wid * 32 + m * 16 + lh * 4 + j;
                w[(size_t)e * 64 + n * 16 + lr] = acc[m][n][j] * s;
            }
}

// ---- edge products: scal (bf16, K-TILED [2][E][64]) + V_out GEMM ----
__launch_bounds__(256)
__global__ void edge_kernel(const int* __restrict__ senders, const float4* __restrict__ agg4,
                            const float4* __restrict__ V4, const u16* __restrict__ Wlt,
                            u16* __restrict__ scal, float* __restrict__ Vout) {
    __shared__ u16 a_lds[3][32][200];
    __shared__ u16 w_lds[64 * 200];
    const int t = threadIdx.x;
    const int e0 = blockIdx.x * 32;
#pragma unroll
    for (int i = 0; i < 6; ++i) {
        int c = i * 256 + t;
        int row = c / 24, off = (c % 24) * 8;
        *(uint4*)((char*)w_lds + row * 400 + off * 2) = ((const uint4*)Wlt)[c];
    }
    const float invs3 = 0.5773502691896258f;
    const float invs2 = 0.7071067811865476f;
    const float EPS = 0.24253562503633297f;
#pragma unroll
    for (int i = 0; i < 8; ++i) {
        int el = i * 4 + (t >> 6);
        int m = t & 63;
        int e = e0 + el;
        int s = senders[e];
        float4 a = agg4[(size_t)s * 64 + m];
        a.x *= EPS; a.y *= EPS; a.z *= EPS; a.w *= EPS;
        float4 b = V4[(size_t)e * 64 + m];
        float s0 = a.x * b.x;
        float s1 = (a.y * b.y + a.z * b.z + a.w * b.w) * invs3;
        scal[(size_t)e * 64 + m] = f2bf(s0);                       // K-tile 0
        scal[(size_t)E_TOT * 64 + (size_t)e * 64 + m] = f2bf(s1);  // K-tile 1
        float cx = (a.z * b.w - a.w * b.z) * invs2;
        float cy = (a.w * b.y - a.y * b.w) * invs2;
        float cz = (a.y * b.z - a.z * b.y) * invs2;
        a_lds[0][el][m] = f2bf(a.x * b.y);
        a_lds[0][el][64 + m] = f2bf(a.y * b.x);
        a_lds[0][el][128 + m] = f2bf(cx);
        a_lds[1][el][m] = f2bf(a.x * b.z);
        a_lds[1][el][64 + m] = f2bf(a.z * b.x);
        a_lds[1][el][128 + m] = f2bf(cy);
        a_lds[2][el][m] = f2bf(a.x * b.w);
        a_lds[2][el][64 + m] = f2bf(a.w * b.x);
        a_lds[2][el][128 + m] = f2bf(cz);
    }
    __syncthreads();
    const int lane = t & 63, wid = t >> 6;
    const int lr = lane & 15, lh = lane >> 4;
    f32x4 acc[3][2] = {};
    for (int kt = 0; kt < 6; ++kt) {
        bf16x8 bfr = *(const bf16x8*)((const char*)w_lds + (wid * 16 + lr) * 400 + kt * 64 + lh * 16);
#pragma unroll
        for (int c = 0; c < 3; ++c)
#pragma unroll
            for (int m = 0; m < 2; ++m) {
                bf16x8 afr = *(const bf16x8*)((const char*)a_lds + ((c * 32 + m * 16 + lr) * 400) + kt * 64 + lh * 16);
                acc[c][m] = __builtin_amdgcn_mfma_f32_16x16x32_bf16(afr, bfr, acc[c][m], 0, 0, 0);
            }
    }
    __syncthreads();
    float* ot = (float*)a_lds;
    const float sc = 0.07216878364870323f; // 1/sqrt(192)
#pragma unroll
    for (int c = 0; c < 3; ++c)
#pragma unroll
        for (int m = 0; m < 2; ++m)
#pragma unroll
            for (int j = 0; j < 4; ++j) {
                int row = m * 16 + lh * 4 + j;
                int mul = wid * 16 + lr;
                ot[row * 192 + mul * 3 + c] = acc[c][m][j] * sc;
            }
    __syncthreads();
    float4* vo = (float4*)(Vout + (size_t)e0 * 192);
#pragma unroll
    for (int i = 0; i < 6; ++i)
        vo[i * 256 + t] = ((float4*)ot)[i * 256 + t];
}

// ---- MLP GEMM v9 (BEST, r16): persistent 256², 16 waves, counted vmcnt,
//      K-TILED activations: A[(ktile*E + row)*64 + col] — each K-step's
//      A-fetch is one CONTIGUOUS 32 KB block.
//      MODE 0 writes K-tiled bf16; MODE 1 writes row-major f32 (final out).
template <int MODE, int K>
__launch_bounds__(1024)
__global__ void mlp_gemm(const u16* __restrict__ A, const u16* __restrict__ A2,
                         const u16* __restrict__ Bt, const float scale,
                         const float* __restrict__ env,
                         u16* __restrict__ outb, float* __restrict__ outf) {
    constexpr int NKT = K >> 6;
    constexpr int NSTEP = NKT * 4; // 4 tiles per block
    __shared__ u16 lds[2][2][256 * 64]; // [dbuf][A/B][row*64+col], 128 KiB
    const int b = blockIdx.x; // 0..255
    const int t = threadIdx.x, lane = t & 63, wid = t >> 6;
    const int wm = wid >> 2, wn = wid & 3;  // 4 x 4 wave grid, wave-tile 64x64
    const int lr = lane & 15, lh = lane >> 4;
    f32x4 acc[4][4] = {};

    auto issue = [&](int g) {
        const int tile = g / NKT;
        const int kt = g - tile * NKT;
        const int tid = b * 4 + tile;       // nt inner: (mt,0),(mt,1),(mt+1,0),...
        const int e0 = (tid >> 1) << 8;
        const int n0 = (tid & 1) << 8;
        const int kk = kt << 6;
        const int buf = g & 1;
        // A (K-tiled): contiguous 32 KB block per step
        const u16* abase;
        size_t arow;
        if (A2 && kk >= 512) { abase = A2; arow = (size_t)((kk - 512) >> 6) * E_TOT + e0; }
        else                 { abase = A;  arow = (size_t)(kk >> 6) * E_TOT + e0; }
#pragma unroll
        for (int i = 0; i < 2; ++i) {
            const int c = i * 1024 + t;
            const int rowin = c >> 3;
            const int scol = ((c & 7) ^ (rowin & 7)) << 3;
            gload16(abase + (arow + rowin) * 64 + scol,
                    (u16*)&lds[buf][0][0] + (size_t)c * 8);
        }
#pragma unroll
        for (int i = 0; i < 2; ++i) {
            const int c = i * 1024 + t;
            const int rowin = c >> 3;
            const int scol = ((c & 7) ^ (rowin & 7)) << 3;
            gload16(Bt + (size_t)(n0 + rowin) * K + kk + scol,
                    (u16*)&lds[buf][1][0] + (size_t)c * 8);
        }
    };

    issue(0);
    issue(1);
    for (int g = 0; g < NSTEP; ++g) {
        const int tile = g / NKT;
        const int kt = g - tile * NKT;
        // fused wait+barrier (one asm unit) — r14 audit
        if (g + 1 >= NSTEP)           asm volatile("s_waitcnt vmcnt(0)\ns_barrier" ::: "memory");
        else if (kt <= 1 && tile > 0) asm volatile("s_waitcnt vmcnt(8)\ns_barrier" ::: "memory");
        else                          asm volatile("s_waitcnt vmcnt(4)\ns_barrier" ::: "memory");
        const u16* Ab = lds[g & 1][0];
        const u16* Bb = lds[g & 1][1];
        __builtin_amdgcn_s_setprio(1);
#pragma unroll
        for (int k2 = 0; k2 < 2; ++k2) {
            bf16x8 af[4], bfr[4];
#pragma unroll
            for (int m = 0; m < 4; ++m)
                af[m] = lds_frag(Ab, wm * 64 + m * 16 + lr, k2 * 64 + lh * 16);
#pragma unroll
            for (int n = 0; n < 4; ++n)
                bfr[n] = lds_frag(Bb, wn * 64 + n * 16 + lr, k2 * 64 + lh * 16);
#pragma unroll
            for (int m = 0; m < 4; ++m)
#pragma unroll
                for (int n = 0; n < 4; ++n)
                    acc[m][n] = __builtin_amdgcn_mfma_f32_16x16x32_bf16(af[m], bfr[n], acc[m][n], 0, 0, 0);
        }
        __builtin_amdgcn_s_setprio(0);
        // all waves' reads of this buffer done -> safe to refill it
        asm volatile("s_waitcnt lgkmcnt(0)\ns_barrier" ::: "memory");
        if (g + 2 < NSTEP) issue(g + 2);
        if (kt == NKT - 1) {
            // epilogue for `tile` (overlaps next tile's in-flight loads)
            const int tid = b * 4 + tile;
            const int e0 = (tid >> 1) << 8;
            const int n0 = (tid & 1) << 8;
#pragma unroll
            for (int m = 0; m < 4; ++m) {
#pragma unroll
                for (int j = 0; j < 4; ++j) {
                    const int row = e0 + wm * 64 + m * 16 + lh * 4 + j;
                    float ev = (MODE == 1) ? env[row] : 0.0f;
#pragma unroll
                    for (int n = 0; n < 4; ++n) {
                        const int col = n0 + wn * 64 + n * 16 + lr;
                        float v = acc[m][n][j] * scale;
                        if (MODE == 0) {
                            float sv = v / (1.0f + __expf(-v));
                            outb[((size_t)(col >> 6) * E_TOT + row) * 64 + (col & 63)] = f2bf(sv);
                        } else {
                            outf[(size_t)row * 512 + col] = v * ev;
                        }
                    }
                }
            }
#pragma unroll
            for (int m = 0; m < 4; ++m)
#pragma unroll
                for (int n = 0; n < 4; ++n)
                    acc[m][n] = f32x4{0.f, 0.f, 0.f, 0.f};
        }
    }
}

extern "C" void kernel_launch(void* const* d_in, const int* in_sizes, int n_in,
                              void* d_out, int out_size, void* d_ws, size_t ws_size,
                              hipStream_t stream) {
    const float* vectors = (const float*)d_in[0];
    const float* x       = (const float*)d_in[1];
    const float* V       = (const float*)d_in[2];
    const int*   senders = (const int*)d_in[3];
    const float* W_w     = (const float*)d_in[4];
    const float* W1      = (const float*)d_in[5];
    const float* W2      = (const float*)d_in[6];
    const float* W3      = (const float*)d_in[7];
    const float* W_lin   = (const float*)d_in[8];
    float* out = (float*)d_out;
    char* ws = (char*)d_ws;

    u16*    XB   = (u16*)(ws + 0x0);          // E*512 bf16 (K-tiled [8][E][64])
    u16*    H1   = (u16*)(ws + 0x8000000);    // E*512 bf16 (K-tiled)
    u16*    SCAL = (u16*)(ws + 0x10000000);   // E*128 bf16 (K-tiled [2][E][64])
    float*  AGG  = (float*)(ws + 0x12000000); // 8192*256 f32
    float*  ENV  = (float*)(ws + 0x12800000); // E f32
    float4* Yb   = (float4*)(ws + 0x12880000);// E float4
    float*  Wbuf = (float*)(ws + 0x12A80000); // E*64 f32
    u16*    WT   = (u16*)(ws + 0x14A80000);   // weights bf16
    u16* Wwt = WT;                 // 64 x 512
    u16* W1t = Wwt + 64 * 512;     // 512 x 640
    u16* W2t = W1t + 512 * 640;    // 512 x 512
    u16* W3t = W2t + 512 * 512;    // 512 x 512
    u16* Wlt = W3t + 512 * 512;    // 64 x 192
    u16* H2 = XB;                  // reuse XB for h2 (K-tiled; GEMM1 done reading)
    // sort scratch
    int* COUNT = (int*)(ws + 0x15000000);     // 8192
    int* OFF   = (int*)(ws + 0x15010000);     // 8193
    int* CURS  = (int*)(ws + 0x15020000);     // 8192
    int* PERM  = (int*)(ws + 0x15030000);     // E

    hipMemsetAsync(COUNT, 0, NNODES * sizeof(int), stream);

    wconv_kernel<<<(64 * 512) / 256, 256, 0, stream>>>(W_w, Wwt, 512, 64);
    wconv_kernel<<<(512 * 640) / 256, 256, 0, stream>>>(W1, W1t, 640, 512);
    wconv_kernel<<<(512 * 512) / 256, 256, 0, stream>>>(W2, W2t, 512, 512);
    wconv_kernel<<<(512 * 512) / 256, 256, 0, stream>>>(W3, W3t, 512, 512);
    wconv_kernel<<<(64 * 192) / 256, 256, 0, stream>>>(W_lin, Wlt, 192, 64);

    envy_kernel<<<E_TOT / 256, 256, 0, stream>>>(vectors, ENV, Yb);

    hist_kernel<<<E_TOT / 256, 256, 0, stream>>>(senders, COUNT);
    scan_kernel<<<1, 1024, 0, stream>>>(COUNT, OFF, CURS);
    permbuild_kernel<<<E_TOT / 256, 256, 0, stream>>>(senders, CURS, PERM);

    // fused x->bf16 conversion (K-tiled XB) + w-GEMM
    wgemm_kernel<<<E_TOT / 128, 256, 0, stream>>>(x, Wwt, XB, Wbuf);
    gather_kernel<<<NNODES / 4, 256, 0, stream>>>(Wbuf, Yb, OFF, PERM, (float4*)AGG);

    edge_kernel<<<E_TOT / 32, 256, 0, stream>>>(senders, (const float4*)AGG, (const float4*)V,
                                                Wlt, SCAL, out + (size_t)E_TOT * 512);

    const float s640 = 0.03952847075210474f;  // 1/sqrt(640)
    const float s512 = 0.044194173824159216f; // 1/sqrt(512)
    // persistent grid: 256 blocks x 4 tiles = 1024 tiles (512 mt x 2 nt)
    mlp_gemm<0, 640><<<256, 1024, 0, stream>>>(XB, SCAL, W1t, s640, nullptr, H1, nullptr);
    mlp_gemm<0, 512><<<256, 1024, 0, stream>>>(H1, nullptr, W2t, s512, nullptr, H2, nullptr);
    mlp_gemm<1, 512><<<256, 1024, 0, stream>>>(H2, nullptr, W3t, s512, ENV, nullptr, out);
}